// Round 1
// baseline (378.732 us; speedup 1.0000x reference)
//
#include <hip/hip_runtime.h>
#include <hip/hip_bf16.h>
#include <stdint.h>

#define N      2048
#define NFEAT  512
#define NHID   64
#define NCLASS 64
#define NHEADS 8
#define ALPHA  0.2f
#define NW     (N / 64)   // 32 bitmask words per row
#define TI     32         // rows per attention block

// ---------------------------------------------------------------- pack adj -> bitmask
__global__ void pack_adj(const int* __restrict__ adj, unsigned long long* __restrict__ bits) {
    int i = blockIdx.x;              // row
    int t = threadIdx.x;             // 256
    int wave = t >> 6, lane = t & 63;
    for (int w = wave; w < NW; w += 4) {
        int j = w * 64 + lane;
        unsigned long long m = __ballot(adj[(size_t)i * N + j] > 0);
        if (lane == 0) bits[(size_t)i * NW + w] = m;
    }
}

// ---------------------------------------------------------------- fp32 tiled GEMM
// C[i][h*64 + n] = sum_k A[i][k] * B[h][k][n];  A:[N][K] row-major, B:[nheads][K][64]
#define BM 64
#define BN 64
#define BK 16
__global__ __launch_bounds__(256) void gemm_heads(const float* __restrict__ A,
                                                  const float* __restrict__ B,
                                                  float* __restrict__ C,
                                                  int K, int ldc) {
    int i0 = blockIdx.x * BM;
    int h  = blockIdx.y;
    const float* Bh = B + (size_t)h * K * 64;
    __shared__ float As[BK][BM + 4];   // 68-float rows: conflict-safe + 16B aligned
    __shared__ float Bs[BK][BN];
    int t  = threadIdx.x;
    int tx = t & 15, ty = t >> 4;
    float acc[4][4] = {};
    for (int k0 = 0; k0 < K; k0 += BK) {
        {   // A tile: 64 rows x 16 k; one float4 per thread
            int row = t >> 2, kq = (t & 3) * 4;
            const float4 av = *reinterpret_cast<const float4*>(&A[(size_t)(i0 + row) * K + k0 + kq]);
            As[kq + 0][row] = av.x; As[kq + 1][row] = av.y;
            As[kq + 2][row] = av.z; As[kq + 3][row] = av.w;
            // B tile: 16 k x 64 n; one float4 per thread
            int kk = t >> 4, n = (t & 15) * 4;
            *reinterpret_cast<float4*>(&Bs[kk][n]) =
                *reinterpret_cast<const float4*>(&Bh[(size_t)(k0 + kk) * 64 + n]);
        }
        __syncthreads();
        #pragma unroll
        for (int k = 0; k < BK; ++k) {
            float4 a = *reinterpret_cast<const float4*>(&As[k][ty * 4]);
            float4 b = *reinterpret_cast<const float4*>(&Bs[k][tx * 4]);
            float av[4] = {a.x, a.y, a.z, a.w};
            float bv[4] = {b.x, b.y, b.z, b.w};
            #pragma unroll
            for (int r = 0; r < 4; ++r)
                #pragma unroll
                for (int c = 0; c < 4; ++c)
                    acc[r][c] += av[r] * bv[c];
        }
        __syncthreads();
    }
    #pragma unroll
    for (int r = 0; r < 4; ++r) {
        float4 v = make_float4(acc[r][0], acc[r][1], acc[r][2], acc[r][3]);
        *reinterpret_cast<float4*>(&C[(size_t)(i0 + ty * 4 + r) * ldc + h * 64 + tx * 4]) = v;
    }
}

// ---------------------------------------------------------------- per-(head,row) score dots
// block = nheads*64 threads; s1[h*N+i] = H[i][h*64+:] . a1[h][:]
__global__ void scores_kernel(const float* __restrict__ Hc, const float* __restrict__ a1,
                              const float* __restrict__ a2, float* __restrict__ s1,
                              float* __restrict__ s2, int ldh) {
    int i = blockIdx.x;
    int t = threadIdx.x;
    int h = t >> 6, d = t & 63;
    (void)d;
    float hv = Hc[(size_t)i * ldh + t];
    float p1 = hv * a1[t];
    float p2 = hv * a2[t];
    #pragma unroll
    for (int off = 32; off; off >>= 1) { p1 += __shfl_xor(p1, off); p2 += __shfl_xor(p2, off); }
    if ((t & 63) == 0) { s1[h * N + i] = p1; s2[h * N + i] = p2; }
}

// ---------------------------------------------------------------- fused masked softmax + PV
// MODE 0: out[i][h*64+d] = elu(att@H)   (layer 1, full row)
// MODE 1: out[(jc*N+i)*64+d] = unnormalized partial, psum[jc*N+i] = partial weight sum
template <int MODE>
__global__ __launch_bounds__(256) void attn_kernel(
        const unsigned long long* __restrict__ bits,
        const float* __restrict__ s1h, const float* __restrict__ s2h,
        const float* __restrict__ H, int ldh,
        float* __restrict__ out, int ldo,
        float* __restrict__ psum, int jc_words) {
    int i0 = blockIdx.x * TI;
    int h  = blockIdx.y;
    int jc = blockIdx.z;
    int t  = threadIdx.x;
    const float* s1 = s1h + (size_t)h * N;
    const float* s2 = s2h + (size_t)h * N;

    __shared__ unsigned long long bitsL[TI][NW];   // 8 KB
    __shared__ float s2L[TI], emaxL[TI], wsumL[TI];
    __shared__ float mred[TI][8];
    __shared__ float w3[TI][68];                   // w[r][jj], padded row (272B, 16B aligned)

    for (int idx = t; idx < TI * NW; idx += 256) {
        int r = idx >> 5, w = idx & 31;
        bitsL[r][w] = bits[(size_t)(i0 + r) * NW + w];
    }
    if (t < TI) s2L[t] = s2[i0 + t];
    __syncthreads();

    // pass 1: masked max of s1 over the FULL row (needed even for partial chunks)
    {
        int r = t >> 3, sub = t & 7;
        float mx = -1e30f;
        for (int w = sub; w < NW; w += 8) {
            unsigned long long word = bitsL[r][w];
            while (word) {
                int b = __ffsll((long long)word) - 1;
                word &= word - 1;
                mx = fmaxf(mx, s1[w * 64 + b]);
            }
        }
        mred[r][sub] = mx;
    }
    __syncthreads();
    if (t < TI) {
        float mx = mred[t][0];
        #pragma unroll
        for (int q = 1; q < 8; ++q) mx = fmaxf(mx, mred[t][q]);
        float e = mx + s2L[t];
        emaxL[t] = (e > 0.f) ? e : ALPHA * e;
    }
    __syncthreads();

    int jj = t & 63, rg = t >> 6;           // rg in [0,4): rows rg*8..rg*8+7
    int jbase = jc * (jc_words * 64);
    float wsum[8] = {};
    float acc[8]  = {};
    int d = jj;                              // FMA phase: this thread's output column

    for (int wi = 0; wi < jc_words; ++wi) {
        int jrow0 = jbase + wi * 64;
        float s1v = s1[jrow0 + jj];
        unsigned long long myword_shift = 0;  // per-row bit below
        __syncthreads();                      // protect w3 from previous tile's readers
        #pragma unroll
        for (int r8 = 0; r8 < 8; ++r8) {
            int r = rg * 8 + r8;
            int bit = (int)((bitsL[r][(jbase >> 6) + wi] >> jj) & 1ULL);
            float e = s1v + s2L[r];
            e = (e > 0.f) ? e : ALPHA * e;
            float w = bit ? __expf(e - emaxL[r]) : 0.f;
            w3[r][jj] = w;
            wsum[r8] += w;
        }
        (void)myword_shift;
        __syncthreads();
        // PV accumulate: thread covers column d for rows rg*8..rg*8+7
        #pragma unroll 4
        for (int jj2 = 0; jj2 < 64; jj2 += 4) {
            float hv[4];
            #pragma unroll
            for (int q = 0; q < 4; ++q)
                hv[q] = H[(size_t)(jrow0 + jj2 + q) * ldh + h * 64 + d];
            #pragma unroll
            for (int r8 = 0; r8 < 8; ++r8) {
                const float4 wv = *reinterpret_cast<const float4*>(&w3[rg * 8 + r8][jj2]);
                acc[r8] += wv.x * hv[0] + wv.y * hv[1] + wv.z * hv[2] + wv.w * hv[3];
            }
        }
    }

    // reduce weight sums across the wave (all 64 lanes of wave rg share the same 8 rows)
    #pragma unroll
    for (int r8 = 0; r8 < 8; ++r8) {
        float s = wsum[r8];
        #pragma unroll
        for (int off = 32; off; off >>= 1) s += __shfl_xor(s, off);
        if (jj == 0) wsumL[rg * 8 + r8] = s;
    }
    __syncthreads();

    if (MODE == 0) {
        #pragma unroll
        for (int r8 = 0; r8 < 8; ++r8) {
            int r = rg * 8 + r8;
            float v = acc[r8] / wsumL[r];
            v = (v > 0.f) ? v : (__expf(v) - 1.f);   // fused elu for layer-2 input
            out[(size_t)(i0 + r) * ldo + h * 64 + d] = v;
        }
    } else {
        #pragma unroll
        for (int r8 = 0; r8 < 8; ++r8) {
            int r = rg * 8 + r8;
            out[((size_t)jc * N + i0 + r) * 64 + d] = acc[r8];
        }
        if (t < TI) psum[(size_t)jc * N + i0 + t] = wsumL[t];
    }
}

// ---------------------------------------------------------------- combine split-j partials
__global__ void combine_kernel(const float* __restrict__ pout, const float* __restrict__ psum,
                               float* __restrict__ outp) {
    int idx = blockIdx.x * 256 + threadIdx.x;   // N*64 total
    int i = idx >> 6;
    float a = 0.f, s = 0.f;
    #pragma unroll
    for (int jc = 0; jc < 4; ++jc) {
        a += pout[((size_t)jc * N + i) * 64 + (idx & 63)];
        s += psum[(size_t)jc * N + i];
    }
    outp[idx] = a / s;
}

// ---------------------------------------------------------------- launch
extern "C" void kernel_launch(void* const* d_in, const int* in_sizes, int n_in,
                              void* d_out, int out_size, void* d_ws, size_t ws_size,
                              hipStream_t stream) {
    const float* x   = (const float*)d_in[0];
    const int*   adj = (const int*)d_in[1];
    const float* W   = (const float*)d_in[2];
    const float* a1  = (const float*)d_in[3];
    const float* a2  = (const float*)d_in[4];
    const float* Wf  = (const float*)d_in[5];
    const float* a1f = (const float*)d_in[6];
    const float* a2f = (const float*)d_in[7];
    float* out = (float*)d_out;

    char* ws = (char*)d_ws;
    unsigned long long* bits = (unsigned long long*)ws; ws += (size_t)N * NW * 8;   // 512 KB
    float* Hcat = (float*)ws; ws += (size_t)N * 512 * 4;                            // 4 MB
    float* x2   = (float*)ws; ws += (size_t)N * 512 * 4;                            // 4 MB
    float* s1   = (float*)ws; ws += (size_t)NHEADS * N * 4;
    float* s2   = (float*)ws; ws += (size_t)NHEADS * N * 4;
    float* H2   = (float*)ws; ws += (size_t)N * 64 * 4;
    float* s1f  = (float*)ws; ws += (size_t)N * 4;
    float* s2f  = (float*)ws; ws += (size_t)N * 4;
    float* pout = (float*)ws; ws += (size_t)4 * N * 64 * 4;                         // 2 MB
    float* psum = (float*)ws; ws += (size_t)4 * N * 4;

    // 1) adjacency -> bitmask
    pack_adj<<<N, 256, 0, stream>>>(adj, bits);
    // 2) per-head projections: Hcat[i][h*64+d]
    gemm_heads<<<dim3(N / BM, NHEADS), 256, 0, stream>>>(x, W, Hcat, NFEAT, 512);
    // 3) score vectors s1,s2 [8][N]
    scores_kernel<<<N, NHEADS * 64, 0, stream>>>(Hcat, a1, a2, s1, s2, 512);
    // 4) layer-1 fused masked softmax + PV + elu -> x2[i][h*64+d]
    attn_kernel<0><<<dim3(N / TI, NHEADS, 1), 256, 0, stream>>>(bits, s1, s2, Hcat, 512,
                                                                x2, 512, nullptr, NW);
    // 5) final projection H2 = x2 @ Wf
    gemm_heads<<<dim3(N / BM, 1), 256, 0, stream>>>(x2, Wf, H2, NHEADS * NHID, 64);
    // 6) final score vectors
    scores_kernel<<<N, 64, 0, stream>>>(H2, a1f, a2f, s1f, s2f, 64);
    // 7) layer-2 attention, split into 4 j-chunks for occupancy
    attn_kernel<1><<<dim3(N / TI, 1, 4), 256, 0, stream>>>(bits, s1f, s2f, H2, 64,
                                                           pout, 64, psum, NW / 4);
    // 8) combine partials -> d_out
    combine_kernel<<<(N * 64) / 256, 256, 0, stream>>>(pout, psum, out);
}

// Round 2
// 128.765 us; speedup vs baseline: 2.9413x; 2.9413x over previous
//
#include <hip/hip_runtime.h>
#include <hip/hip_bf16.h>
#include <stdint.h>

#define N      2048
#define NFEAT  512
#define NHID   64
#define NCLASS 64
#define NHEADS 8
#define ALPHA  0.2f
#define NW     (N / 64)   // 32 bitmask words per row

typedef __attribute__((ext_vector_type(8))) short bf16x8;
typedef __attribute__((ext_vector_type(4))) float f32x4;

__device__ __forceinline__ short f2bf(float f) {
    union { float f; unsigned u; } v; v.f = f;
    unsigned r = v.u + 0x7fffu + ((v.u >> 16) & 1u);   // RNE
    return (short)(r >> 16);
}
__device__ __forceinline__ float bf2f(short s) {
    union { unsigned u; float f; } v; v.u = ((unsigned)(unsigned short)s) << 16;
    return v.f;
}
__device__ __forceinline__ unsigned pack2(float a, float b) {
    return (unsigned)(unsigned short)f2bf(a) | ((unsigned)(unsigned short)f2bf(b) << 16);
}

// ---------------------------------------------------------------- pack adj -> bitmask
__global__ void pack_adj(const int* __restrict__ adj, unsigned long long* __restrict__ bits) {
    int i = blockIdx.x;
    int t = threadIdx.x;
    int wave = t >> 6, lane = t & 63;
    for (int w = wave; w < NW; w += 4) {
        int j = w * 64 + lane;
        unsigned long long m = __ballot(adj[(size_t)i * N + j] > 0);
        if (lane == 0) bits[(size_t)i * NW + w] = m;
    }
}

// ---------------------------------------------------------------- f32 -> bf16 (row-major)
__global__ void cvt_f32_bf16(const float* __restrict__ in, short* __restrict__ out, int n8) {
    int idx = blockIdx.x * 256 + threadIdx.x;
    if (idx >= n8) return;
    const float4 a = ((const float4*)in)[idx * 2];
    const float4 b = ((const float4*)in)[idx * 2 + 1];
    ((uint4*)out)[idx] = make_uint4(pack2(a.x, a.y), pack2(a.z, a.w),
                                    pack2(b.x, b.y), pack2(b.z, b.w));
}

// ---------------------------------------------------------------- [h][R][64] f32 -> [h][64][R] bf16
__global__ __launch_bounds__(256) void transpose_cvt(const float* __restrict__ in,
                                                     short* __restrict__ out,
                                                     int R, int inHS, int outHS) {
    __shared__ float tile[64][65];
    int h  = blockIdx.y;
    int r0 = blockIdx.x * 64;
    int t  = threadIdx.x;
    {
        int r = t >> 2, cq = (t & 3) * 16;
        const float* src = in + (size_t)h * inHS + (size_t)(r0 + r) * 64 + cq;
        #pragma unroll
        for (int q = 0; q < 4; ++q) {
            float4 v = ((const float4*)src)[q];
            tile[r][cq + q * 4 + 0] = v.x; tile[r][cq + q * 4 + 1] = v.y;
            tile[r][cq + q * 4 + 2] = v.z; tile[r][cq + q * 4 + 3] = v.w;
        }
    }
    __syncthreads();
    {
        int c = t >> 2, rq = (t & 3) * 16;
        unsigned u[8];
        #pragma unroll
        for (int p = 0; p < 8; ++p)
            u[p] = pack2(tile[rq + 2 * p][c], tile[rq + 2 * p + 1][c]);
        short* dst = out + (size_t)h * outHS + (size_t)c * R + r0 + rq;
        ((uint4*)dst)[0] = make_uint4(u[0], u[1], u[2], u[3]);
        ((uint4*)dst)[1] = make_uint4(u[4], u[5], u[6], u[7]);
    }
}

// ---------------------------------------------------------------- bf16 MFMA GEMM
// Ab [M][K] bf16 row-major; Btb [h][64][K] bf16 (B^T rows); Ctb [h*64+n][M] bf16 (transposed!)
template <int RT>
__global__ __launch_bounds__(256) void gemm_mfma(const short* __restrict__ Ab,
                                                 const short* __restrict__ Btb,
                                                 short* __restrict__ Ctb,
                                                 int M, int K) {
    const int h = blockIdx.y;
    const int t = threadIdx.x, wave = t >> 6, lane = t & 63;
    const int c = lane & 15, g = lane >> 4;
    const int i0 = blockIdx.x * (4 * RT * 16) + wave * (RT * 16);
    const short* Bh = Btb + (size_t)h * 64 * K;
    f32x4 acc[RT][4];
    #pragma unroll
    for (int rt = 0; rt < RT; ++rt)
        #pragma unroll
        for (int dt = 0; dt < 4; ++dt) { acc[rt][dt][0]=0.f; acc[rt][dt][1]=0.f; acc[rt][dt][2]=0.f; acc[rt][dt][3]=0.f; }
    for (int k0 = 0; k0 < K; k0 += 32) {
        bf16x8 af[RT];
        #pragma unroll
        for (int rt = 0; rt < RT; ++rt)
            af[rt] = *(const bf16x8*)(Ab + (size_t)(i0 + rt * 16 + c) * K + k0 + g * 8);
        #pragma unroll
        for (int dt = 0; dt < 4; ++dt) {
            bf16x8 bf = *(const bf16x8*)(Bh + (size_t)(dt * 16 + c) * K + k0 + g * 8);
            #pragma unroll
            for (int rt = 0; rt < RT; ++rt)
                acc[rt][dt] = __builtin_amdgcn_mfma_f32_16x16x32_bf16(af[rt], bf, acc[rt][dt], 0, 0, 0);
        }
    }
    #pragma unroll
    for (int rt = 0; rt < RT; ++rt)
        #pragma unroll
        for (int dt = 0; dt < 4; ++dt) {
            int n = dt * 16 + c;
            int i = i0 + rt * 16 + g * 4;
            uint2 u = make_uint2(pack2(acc[rt][dt][0], acc[rt][dt][1]),
                                 pack2(acc[rt][dt][2], acc[rt][dt][3]));
            *(uint2*)(Ctb + (size_t)(h * 64 + n) * M + i) = u;
        }
}

// ---------------------------------------------------------------- s1,s2 from transposed bf16 H
__global__ void scores_t(const short* __restrict__ Htb, const float* __restrict__ a1,
                         const float* __restrict__ a2, float* __restrict__ s1,
                         float* __restrict__ s2) {
    int h = blockIdx.y;
    int i = blockIdx.x * 256 + threadIdx.x;
    float p1 = 0.f, p2 = 0.f;
    #pragma unroll 8
    for (int d = 0; d < 64; ++d) {
        float hv = bf2f(Htb[(size_t)(h * 64 + d) * N + i]);
        p1 += hv * a1[h * 64 + d];
        p2 += hv * a2[h * 64 + d];
    }
    s1[h * N + i] = p1;
    s2[h * N + i] = p2;
}

// ---------------------------------------------------------------- per-row masked max -> emax
// emax[h][i] = LeakyReLU(max_{j: adj} s1[h][j] + s2[h][i])   (LR is monotone)
__global__ void rowmax_k(const unsigned long long* __restrict__ bits,
                         const float* __restrict__ s1h, const float* __restrict__ s2h,
                         float* __restrict__ emaxh) {
    int gid  = blockIdx.x * 4 + (threadIdx.x >> 6);
    int lane = threadIdx.x & 63;
    int h = gid >> 11;            // / N
    int i = gid & (N - 1);
    const float* s1 = s1h + (size_t)h * N;
    unsigned long long word = bits[(size_t)i * NW + (lane >> 1)];
    unsigned hw = (lane & 1) ? (unsigned)(word >> 32) : (unsigned)word;
    int j0 = lane * 32;
    float mx = -3e38f;
    #pragma unroll
    for (int q = 0; q < 8; ++q) {
        float4 v = *(const float4*)(s1 + j0 + q * 4);
        if ((hw >> (q * 4 + 0)) & 1) mx = fmaxf(mx, v.x);
        if ((hw >> (q * 4 + 1)) & 1) mx = fmaxf(mx, v.y);
        if ((hw >> (q * 4 + 2)) & 1) mx = fmaxf(mx, v.z);
        if ((hw >> (q * 4 + 3)) & 1) mx = fmaxf(mx, v.w);
    }
    #pragma unroll
    for (int off = 32; off; off >>= 1) mx = fmaxf(mx, __shfl_xor(mx, off));
    if (lane == 0) {
        float e = mx + s2h[(size_t)h * N + i];
        emaxh[(size_t)h * N + i] = fmaxf(e, ALPHA * e);
    }
}

// ---------------------------------------------------------------- fused masked-softmax + PV via MFMA
// Block: 4 waves share the same RT*16 rows; j is split across waves (stride-4 chunks of 32).
// A-frag (weights) computed in-register in MFMA lane layout; B-frag = 16B load from Htb[d][j].
// MODE 0: write x2b bf16 = elu(att@H) at [i][h*64+d]; MODE 1: fp32 partials + psum (z-split).
template <int RT, int MODE>
__global__ __launch_bounds__(256) void attn_mfma(
        const unsigned long long* __restrict__ bits,
        const float* __restrict__ s1h, const float* __restrict__ s2h,
        const float* __restrict__ emaxh,
        const short* __restrict__ Htb,
        short* __restrict__ outB, float* __restrict__ outF, float* __restrict__ psum,
        int jwords_per_z) {
    const int h = blockIdx.y;
    const int z = blockIdx.z;
    const int i0 = blockIdx.x * (RT * 16);
    const int t = threadIdx.x;
    const int wave = t >> 6, lane = t & 63;
    const int c = lane & 15, g = lane >> 4;

    const float* s1 = s1h + (size_t)h * N;
    const unsigned long long* brow[RT];
    float s2v[RT], emv[RT];
    #pragma unroll
    for (int rt = 0; rt < RT; ++rt) {
        int i = i0 + rt * 16 + c;
        brow[rt] = bits + (size_t)i * NW;
        s2v[rt] = s2h[(size_t)h * N + i];
        emv[rt] = emaxh[(size_t)h * N + i];
    }

    f32x4 acc[RT][4];
    #pragma unroll
    for (int rt = 0; rt < RT; ++rt)
        #pragma unroll
        for (int dt = 0; dt < 4; ++dt) { acc[rt][dt][0]=0.f; acc[rt][dt][1]=0.f; acc[rt][dt][2]=0.f; acc[rt][dt][3]=0.f; }
    float wsum[RT];
    #pragma unroll
    for (int rt = 0; rt < RT; ++rt) wsum[rt] = 0.f;

    const int nchunk = jwords_per_z * 2;
    const int cbase  = z * nchunk;
    for (int cc = wave; cc < nchunk; cc += 4) {
        const int j0 = (cbase + cc) * 32;
        const int wi = j0 >> 6;
        const int sh = (j0 & 32) + g * 8;
        const float4 q0 = *(const float4*)(s1 + j0 + g * 8);
        const float4 q1 = *(const float4*)(s1 + j0 + g * 8 + 4);
        const float s1e[8] = {q0.x, q0.y, q0.z, q0.w, q1.x, q1.y, q1.z, q1.w};
        bf16x8 af[RT];
        #pragma unroll
        for (int rt = 0; rt < RT; ++rt) {
            unsigned byte = (unsigned)(brow[rt][wi] >> sh) & 0xffu;
            #pragma unroll
            for (int e = 0; e < 8; ++e) {
                float ev = s1e[e] + s2v[rt];
                ev = fmaxf(ev, ALPHA * ev);                       // LeakyReLU
                float w = ((byte >> e) & 1u) ? __expf(ev - emv[rt]) : 0.f;
                wsum[rt] += w;
                af[rt][e] = f2bf(w);
            }
        }
        #pragma unroll
        for (int dt = 0; dt < 4; ++dt) {
            bf16x8 bf = *(const bf16x8*)(Htb + (size_t)(h * 64 + dt * 16 + c) * N + j0 + g * 8);
            #pragma unroll
            for (int rt = 0; rt < RT; ++rt)
                acc[rt][dt] = __builtin_amdgcn_mfma_f32_16x16x32_bf16(af[rt], bf, acc[rt][dt], 0, 0, 0);
        }
    }

    // wsum: combine the 4 lane-groups (same row c)
    #pragma unroll
    for (int rt = 0; rt < RT; ++rt) {
        wsum[rt] += __shfl_xor(wsum[rt], 16);
        wsum[rt] += __shfl_xor(wsum[rt], 32);
    }

    __shared__ float redC[4][RT * 16][66];
    __shared__ float redS[4][RT * 16];
    __shared__ float wsumL[RT * 16];
    #pragma unroll
    for (int rt = 0; rt < RT; ++rt) {
        if (g == 0) redS[wave][rt * 16 + c] = wsum[rt];
        #pragma unroll
        for (int dt = 0; dt < 4; ++dt)
            #pragma unroll
            for (int r = 0; r < 4; ++r)
                redC[wave][rt * 16 + g * 4 + r][dt * 16 + c] = acc[rt][dt][r];
    }
    __syncthreads();
    if (t < RT * 16) wsumL[t] = redS[0][t] + redS[1][t] + redS[2][t] + redS[3][t];
    __syncthreads();

    for (int idx = t; idx < RT * 16 * 64; idx += 256) {
        int r = idx >> 6, d = idx & 63;
        float v = redC[0][r][d] + redC[1][r][d] + redC[2][r][d] + redC[3][r][d];
        if (MODE == 0) {
            v /= wsumL[r];
            v = v > 0.f ? v : (__expf(v) - 1.f);                  // fused elu
            outB[(size_t)(i0 + r) * (NHEADS * NHID) + h * 64 + d] = f2bf(v);
        } else {
            outF[((size_t)z * N + i0 + r) * 64 + d] = v;          // unnormalized partial
        }
    }
    if (MODE == 1 && t < RT * 16) psum[(size_t)z * N + i0 + t] = wsumL[t];
}

// ---------------------------------------------------------------- combine 2 j-partials
__global__ void combine2(const float* __restrict__ pout, const float* __restrict__ psum,
                         float* __restrict__ outp) {
    int idx = blockIdx.x * 256 + threadIdx.x;   // N*64
    int i = idx >> 6;
    float a = pout[idx] + pout[(size_t)N * 64 + idx];
    float s = psum[i] + psum[N + i];
    outp[idx] = a / s;
}

// ---------------------------------------------------------------- launch
extern "C" void kernel_launch(void* const* d_in, const int* in_sizes, int n_in,
                              void* d_out, int out_size, void* d_ws, size_t ws_size,
                              hipStream_t stream) {
    const float* x   = (const float*)d_in[0];
    const int*   adj = (const int*)d_in[1];
    const float* W   = (const float*)d_in[2];
    const float* a1  = (const float*)d_in[3];
    const float* a2  = (const float*)d_in[4];
    const float* Wf  = (const float*)d_in[5];
    const float* a1f = (const float*)d_in[6];
    const float* a2f = (const float*)d_in[7];
    float* out = (float*)d_out;

    char* ws = (char*)d_ws;
    unsigned long long* bits = (unsigned long long*)ws; ws += (size_t)N * NW * 8;  // 512 KB
    short* xb   = (short*)ws; ws += (size_t)N * 512 * 2;        // 2 MB
    short* Wtb  = (short*)ws; ws += (size_t)8 * 64 * 512 * 2;   // 512 KB
    short* Wftb = (short*)ws; ws += (size_t)64 * 512 * 2;       // 64 KB
    short* Htb  = (short*)ws; ws += (size_t)512 * N * 2;        // 2 MB  [h*64+d][j]
    short* x2b  = (short*)ws; ws += (size_t)N * 512 * 2;        // 2 MB  [i][h*64+d]
    short* H2tb = (short*)ws; ws += (size_t)64 * N * 2;         // 256 KB
    float* s1   = (float*)ws; ws += (size_t)NHEADS * N * 4;
    float* s2   = (float*)ws; ws += (size_t)NHEADS * N * 4;
    float* emax = (float*)ws; ws += (size_t)NHEADS * N * 4;
    float* s1f  = (float*)ws; ws += (size_t)N * 4;
    float* s2f  = (float*)ws; ws += (size_t)N * 4;
    float* emaxf= (float*)ws; ws += (size_t)N * 4;
    float* pout = (float*)ws; ws += (size_t)2 * N * 64 * 4;     // 1 MB
    float* psum = (float*)ws; ws += (size_t)2 * N * 4;

    pack_adj<<<N, 256, 0, stream>>>(adj, bits);
    cvt_f32_bf16<<<(N * 512 / 8 + 255) / 256, 256, 0, stream>>>(x, xb, N * 512 / 8);
    transpose_cvt<<<dim3(8, 8), 256, 0, stream>>>(W,  Wtb,  512, 512 * 64, 64 * 512);
    transpose_cvt<<<dim3(8, 1), 256, 0, stream>>>(Wf, Wftb, 512, 0, 0);

    // layer 1: H = x@W  (transposed bf16 out), scores, rowmax, fused attn+elu
    gemm_mfma<2><<<dim3(16, 8), 256, 0, stream>>>(xb, Wtb, Htb, N, 512);
    scores_t<<<dim3(N / 256, 8), 256, 0, stream>>>(Htb, a1, a2, s1, s2);
    rowmax_k<<<(N * 8) / 4, 256, 0, stream>>>(bits, s1, s2, emax);
    attn_mfma<2, 0><<<dim3(N / 32, 8, 1), 256, 0, stream>>>(bits, s1, s2, emax, Htb,
                                                            x2b, nullptr, nullptr, NW);
    // layer 2
    gemm_mfma<2><<<dim3(16, 1), 256, 0, stream>>>(x2b, Wftb, H2tb, N, 512);
    scores_t<<<dim3(N / 256, 1), 256, 0, stream>>>(H2tb, a1f, a2f, s1f, s2f);
    rowmax_k<<<(N * 1) / 4, 256, 0, stream>>>(bits, s1f, s2f, emaxf);
    attn_mfma<1, 1><<<dim3(N / 16, 1, 2), 256, 0, stream>>>(bits, s1f, s2f, emaxf, H2tb,
                                                            nullptr, pout, psum, NW / 2);
    combine2<<<(N * 64) / 256, 256, 0, stream>>>(pout, psum, out);
}